// Round 5
// baseline (1309.099 us; speedup 1.0000x reference)
//
#include <hip/hip_runtime.h>
#include <math.h>

// E88 FLA Hybrid: split-bf16 MFMA qkv GEMM -> prep -> tanh scan -> split-bf16 MFMA out GEMM
// T=2048 B=4 DIM=1024 H=8 NS=64 HV=64 KEY_DIM=512 VAL_DIM=512

#define T_DIM 2048
#define B_DIM 4
#define DIMSZ 1024
#define NH 8
#define KEY_DIM 512
#define VAL_DIM 512
#define ROWS (T_DIM * B_DIM)   // 8192
#define QKV_N 1536
#define N1_PAD 1664            // 13 * 128 (qkv 1536 + a 8 + zero pad)
#define EPS_F 1e-6f

typedef __attribute__((ext_vector_type(8))) short bfx8;   // 8 bf16 in 4 VGPRs
typedef __attribute__((ext_vector_type(4))) float f32x4;  // MFMA accumulator

// ---------------------------------------------------------------------------
__device__ __forceinline__ float tanh_fast(float x) {
    float e = __expf(2.0f * x);
    float r = __builtin_amdgcn_rcpf(e + 1.0f);
    return 1.0f - 2.0f * r;
}

// async global->LDS, 16B per lane; LDS dest = wave-uniform base + lane*16
__device__ __forceinline__ void gload16(const void* g, void* l) {
    __builtin_amdgcn_global_load_lds(
        (const __attribute__((address_space(1))) void*)g,
        (__attribute__((address_space(3))) void*)l, 16, 0, 0);
}

// RNE f32 -> bf16 (bit pattern) + the rounded-back float
__device__ __forceinline__ unsigned short bf16_rne(float x, float& back) {
    unsigned int u = __float_as_uint(x);
    unsigned int r = u + 0x7FFFu + ((u >> 16) & 1u);
    unsigned short h = (unsigned short)(r >> 16);
    back = __uint_as_float((unsigned int)h << 16);
    return h;
}

__device__ __forceinline__ void split_one(float x, unsigned short& h, unsigned short& l) {
    float hf;
    h = bf16_rne(x, hf);
    float rem = x - hf;
    float lf;
    l = bf16_rne(rem, lf);
}

// ---------------------------------------------------------------------------
// Generic f32 -> (hi,lo) bf16 split, float4-vectorized, grid-stride.
__global__ __launch_bounds__(256) void split4_kernel(
    const float* __restrict__ src, unsigned short* __restrict__ hi,
    unsigned short* __restrict__ lo, int nq)
{
    for (int i = blockIdx.x * blockDim.x + threadIdx.x; i < nq;
         i += gridDim.x * blockDim.x) {
        float4 v = ((const float4*)src)[i];
        ushort4 h, l;
        split_one(v.x, h.x, l.x);
        split_one(v.y, h.y, l.y);
        split_one(v.z, h.z, l.z);
        split_one(v.w, h.w, l.w);
        ((ushort4*)hi)[i] = h;
        ((ushort4*)lo)[i] = l;
    }
}

// Build padded B for GEMM1: rows 0..1535 = W_qkv, 1536..1543 = W_a, rest 0.
__global__ __launch_bounds__(256) void wcat_split_kernel(
    const float* __restrict__ Wqkv, const float* __restrict__ Wa,
    unsigned short* __restrict__ hi, unsigned short* __restrict__ lo)
{
    int q = blockIdx.x * 256 + threadIdx.x;   // quad index; grid covers exactly
    int row = q >> 8;                         // 256 quads per 1024-col row
    int cq = q & 255;
    float4 v = make_float4(0.f, 0.f, 0.f, 0.f);
    if (row < QKV_N)           v = ((const float4*)(Wqkv + (size_t)row * DIMSZ))[cq];
    else if (row < QKV_N + NH) v = ((const float4*)(Wa + (size_t)(row - QKV_N) * DIMSZ))[cq];
    ushort4 h, l;
    split_one(v.x, h.x, l.x);
    split_one(v.y, h.y, l.y);
    split_one(v.z, h.z, l.z);
    split_one(v.w, h.w, l.w);
    ((ushort4*)hi)[q] = h;
    ((ushort4*)lo)[q] = l;
}

// ---------------------------------------------------------------------------
// Split-bf16 MFMA GEMM: C(MxN) = (Ah+Al)(MxK) * (Wh+Wl)(NxK)^T, dropping lo*lo.
// 128x128 tile, BK=32, 4 waves (2x2), per-wave 64x64 = 4x4 fragments of 16x16.
// LDS is fragment-ordered, lane-linear: subtile fi at fi*1024B, lane l's 16B at
// +l*16 -> exactly global_load_lds's wave-uniform-base + lane*size semantics.
// MODE 0: plain store to out0 (stride DIMSZ). MODE 1: qkv/abuf seam at col 1536.
template<int MODE>
__global__ __launch_bounds__(256) void mfma_gemm_kernel(
    const unsigned short* __restrict__ Ah, const unsigned short* __restrict__ Al,
    const unsigned short* __restrict__ Wh, const unsigned short* __restrict__ Wl,
    float* __restrict__ out0, float* __restrict__ out1, int K)
{
    __shared__ __align__(16) unsigned short Ahs[4096], Als[4096], Bhs[4096], Bls[4096];
    const int tid = threadIdx.x;
    const int lane = tid & 63;
    const int wid = tid >> 6;
    const int wr = wid >> 1, wc = wid & 1;
    const int row0 = blockIdx.y * 128;
    const int col0 = blockIdx.x * 128;
    const int m = lane & 15;        // row within 16-row subtile
    const int kh = lane >> 4;       // which 8-wide k slice of BK=32

    f32x4 acc[4][4] = {};

    for (int k0 = 0; k0 < K; k0 += 32) {
        // stage via async DMA: wave w, pass p covers subtile fi = p*4+w of all
        // four matrices. Per-lane global addr carries the fragment permutation.
        #pragma unroll
        for (int p = 0; p < 2; ++p) {
            int fi = p * 4 + wid;
            size_t ga = (size_t)(row0 + fi * 16 + m) * K + (k0 + kh * 8);
            size_t gb = (size_t)(col0 + fi * 16 + m) * K + (k0 + kh * 8);
            gload16(&Ah[ga], &Ahs[fi * 512]);
            gload16(&Al[ga], &Als[fi * 512]);
            gload16(&Wh[gb], &Bhs[fi * 512]);
            gload16(&Wl[gb], &Bls[fi * 512]);
        }
        __syncthreads();   // compiler drains vmcnt before s_barrier

        bfx8 ah[4], al[4], bh[4], bl[4];
        #pragma unroll
        for (int i = 0; i < 4; ++i) {
            ah[i] = *(const bfx8*)&Ahs[(wr * 4 + i) * 512 + lane * 8];
            al[i] = *(const bfx8*)&Als[(wr * 4 + i) * 512 + lane * 8];
            bh[i] = *(const bfx8*)&Bhs[(wc * 4 + i) * 512 + lane * 8];
            bl[i] = *(const bfx8*)&Bls[(wc * 4 + i) * 512 + lane * 8];
        }
        #pragma unroll
        for (int mi = 0; mi < 4; ++mi)
            #pragma unroll
            for (int ni = 0; ni < 4; ++ni) {
                acc[mi][ni] = __builtin_amdgcn_mfma_f32_16x16x32_bf16(ah[mi], bh[ni], acc[mi][ni], 0, 0, 0);
                acc[mi][ni] = __builtin_amdgcn_mfma_f32_16x16x32_bf16(ah[mi], bl[ni], acc[mi][ni], 0, 0, 0);
                acc[mi][ni] = __builtin_amdgcn_mfma_f32_16x16x32_bf16(al[mi], bh[ni], acc[mi][ni], 0, 0, 0);
            }
        __syncthreads();
    }

    // C/D layout (m89-verified): col = lane&15, row = (lane>>4)*4 + reg
    #pragma unroll
    for (int mi = 0; mi < 4; ++mi)
        #pragma unroll
        for (int ni = 0; ni < 4; ++ni) {
            int crow = row0 + wr * 64 + mi * 16 + (lane >> 4) * 4;
            int ccol = col0 + wc * 64 + ni * 16 + (lane & 15);
            if (MODE == 0) {
                #pragma unroll
                for (int r = 0; r < 4; ++r)
                    out0[(size_t)(crow + r) * DIMSZ + ccol] = acc[mi][ni][r];
            } else {
                if (ccol < QKV_N) {
                    #pragma unroll
                    for (int r = 0; r < 4; ++r)
                        out0[(size_t)(crow + r) * QKV_N + ccol] = acc[mi][ni][r];
                } else if (ccol < QKV_N + NH) {
                    #pragma unroll
                    for (int r = 0; r < 4; ++r)
                        out1[(size_t)(crow + r) * NH + (ccol - QKV_N)] = acc[mi][ni][r];
                }
            }
        }
}

// ---------------------------------------------------------------------------
// Prep: in-place l2norm of q,k head-chunks, silu on v, decay from a.
__global__ __launch_bounds__(64) void prep_kernel(
    float* __restrict__ qkv, float* __restrict__ abuf,
    const float* __restrict__ A_log, const float* __restrict__ dt_bias)
{
    const int row = blockIdx.x;
    const int lane = threadIdx.x;
    float* base = qkv + (size_t)row * QKV_N;

    #pragma unroll
    for (int c = 0; c < 16; ++c) {
        float x = base[c * 64 + lane];
        float s = x * x;
        #pragma unroll
        for (int m = 1; m < 64; m <<= 1) s += __shfl_xor(s, m);
        float inv = 1.0f / sqrtf(s + EPS_F);
        base[c * 64 + lane] = x * inv;
    }
    #pragma unroll
    for (int c = 0; c < 8; ++c) {
        float xv = base[1024 + c * 64 + lane];
        float sg = 1.0f / (1.0f + expf(-xv));
        base[1024 + c * 64 + lane] = xv * sg;
    }
    if (lane < NH) {
        float a = abuf[(size_t)row * NH + lane] + dt_bias[lane];
        float sp = fmaxf(a, 0.0f) + log1pf(expf(-fabsf(a)));
        float d = expf(-expf(A_log[lane]) * sp);
        abuf[(size_t)row * NH + lane] = d;
    }
}

// ---------------------------------------------------------------------------
// Scan: one wave per (b,h,d); lane n owns S[n,d]. Only S carries the
// t-dependency; unroll 4 overlaps the independent butterfly chains.
__global__ __launch_bounds__(64) void scan_kernel(
    const float* __restrict__ qkv, const float* __restrict__ dbuf,
    float* __restrict__ outs)
{
    const int bi = blockIdx.x;
    const int d = bi & 63;
    const int h = (bi >> 6) & 7;
    const int b = bi >> 9;
    const int lane = threadIdx.x;

    size_t qoff = (size_t)b * QKV_N + h * 64 + lane;
    size_t koff = qoff + KEY_DIM;
    size_t voff = (size_t)b * QKV_N + 1024 + h * 64 + d;
    size_t doff = (size_t)b * NH + h;
    size_t ooff = (size_t)b * VAL_DIM + h * 64 + d;
    const size_t qstride = (size_t)B_DIM * QKV_N;
    const size_t dstride = (size_t)B_DIM * NH;
    const size_t ostride = (size_t)B_DIM * VAL_DIM;

    float S = 0.0f;
    #pragma unroll 4
    for (int t = 0; t < T_DIM; ++t) {
        float k = qkv[koff];
        float q = qkv[qoff];
        float v = qkv[voff];
        float dc = dbuf[doff];
        S = tanh_fast(fmaf(dc, S, k * v));
        float p = q * S;
        #pragma unroll
        for (int m = 1; m < 64; m <<= 1) p += __shfl_xor(p, m);
        if (lane == 0) outs[ooff] = p;
        qoff += qstride; koff += qstride; voff += qstride;
        doff += dstride; ooff += ostride;
    }
}

// ---------------------------------------------------------------------------
extern "C" void kernel_launch(void* const* d_in, const int* in_sizes, int n_in,
                              void* d_out, int out_size, void* d_ws, size_t ws_size,
                              hipStream_t stream) {
    const float* x       = (const float*)d_in[0];
    const float* Wqkv    = (const float*)d_in[1];
    const float* Wa      = (const float*)d_in[2];
    const float* A_log   = (const float*)d_in[3];
    const float* dt_bias = (const float*)d_in[4];
    const float* Wout    = (const float*)d_in[5];
    float* out = (float*)d_out;

    char* w = (char*)d_ws;
    float* qkv  = (float*)w;                             // 8192*1536*4 = 50,331,648
    float* abuf = (float*)(w + 50331648);                // 8192*8*4    = 262,144
    float* outs = (float*)(w + 50593792);                // 8192*512*4  = 16,777,216
    unsigned short* xh = (unsigned short*)(w + 67371008);   // 16,777,216
    unsigned short* xl = (unsigned short*)(w + 84148224);   // 16,777,216
    unsigned short* wh = (unsigned short*)(w + 100925440);  // 1664*1024*2 = 3,407,872
    unsigned short* wl = (unsigned short*)(w + 104333312);  // 3,407,872  (end ~102.8 MiB)
    // xh/xl region reused after gemm1 (stream-ordered):
    unsigned short* oh    = (unsigned short*)(w + 67371008); // 8,388,608
    unsigned short* ol    = (unsigned short*)(w + 75759616); // 8,388,608
    unsigned short* wouth = (unsigned short*)(w + 84148224); // 1,048,576
    unsigned short* woutl = (unsigned short*)(w + 85196800); // 1,048,576

    // hi/lo splits of x and [Wqkv;Wa;pad]
    split4_kernel<<<2048, 256, 0, stream>>>(x, xh, xl, ROWS * DIMSZ / 4);
    wcat_split_kernel<<<N1_PAD, 256, 0, stream>>>(Wqkv, Wa, wh, wl);
    // GEMM1: [8192 x 1024] * [1664 x 1024]^T -> qkv + abuf
    mfma_gemm_kernel<1><<<dim3(N1_PAD / 128, ROWS / 128), 256, 0, stream>>>(
        xh, xl, wh, wl, qkv, abuf, DIMSZ);
    prep_kernel<<<ROWS, 64, 0, stream>>>(qkv, abuf, A_log, dt_bias);
    scan_kernel<<<B_DIM * NH * 64, 64, 0, stream>>>(qkv, abuf, outs);
    // splits for GEMM2 (reuse x-split region)
    split4_kernel<<<1024, 256, 0, stream>>>(outs, oh, ol, ROWS * VAL_DIM / 4);
    split4_kernel<<<512, 256, 0, stream>>>(Wout, wouth, woutl, DIMSZ * VAL_DIM / 4);
    // GEMM2: [8192 x 512] * [1024 x 512]^T -> out
    mfma_gemm_kernel<0><<<dim3(DIMSZ / 128, ROWS / 128), 256, 0, stream>>>(
        oh, ol, wouth, woutl, out, nullptr, VAL_DIM);
}

// Round 6
// 926.051 us; speedup vs baseline: 1.4136x; 1.4136x over previous
//
#include <hip/hip_runtime.h>
#include <math.h>

// E88 FLA Hybrid: split-bf16 MFMA qkv GEMM -> prep -> tanh scan -> split-bf16 MFMA out GEMM
// T=2048 B=4 DIM=1024 H=8 NS=64 HV=64 KEY_DIM=512 VAL_DIM=512

#define T_DIM 2048
#define B_DIM 4
#define DIMSZ 1024
#define NH 8
#define KEY_DIM 512
#define VAL_DIM 512
#define ROWS (T_DIM * B_DIM)   // 8192
#define QKV_N 1536
#define N1_PAD 1664            // 13 * 128 (qkv 1536 + a 8 + zero pad)
#define EPS_F 1e-6f

typedef __attribute__((ext_vector_type(8))) short bfx8;   // 8 bf16 in 4 VGPRs
typedef __attribute__((ext_vector_type(4))) float f32x4;  // MFMA accumulator

// ---------------------------------------------------------------------------
// async global->LDS, 16B per lane; LDS dest = wave-uniform base + lane*16
__device__ __forceinline__ void gload16(const void* g, void* l) {
    __builtin_amdgcn_global_load_lds(
        (const __attribute__((address_space(1))) void*)g,
        (__attribute__((address_space(3))) void*)l, 16, 0, 0);
}

// RNE f32 -> bf16 (bit pattern) + the rounded-back float
__device__ __forceinline__ unsigned short bf16_rne(float x, float& back) {
    unsigned int u = __float_as_uint(x);
    unsigned int r = u + 0x7FFFu + ((u >> 16) & 1u);
    unsigned short h = (unsigned short)(r >> 16);
    back = __uint_as_float((unsigned int)h << 16);
    return h;
}

__device__ __forceinline__ void split_one(float x, unsigned short& h, unsigned short& l) {
    float hf;
    h = bf16_rne(x, hf);
    float rem = x - hf;
    float lf;
    l = bf16_rne(rem, lf);
}

// ---------------------------------------------------------------------------
// Generic f32 -> (hi,lo) bf16 split, float4-vectorized, grid-stride.
__global__ __launch_bounds__(256) void split4_kernel(
    const float* __restrict__ src, unsigned short* __restrict__ hi,
    unsigned short* __restrict__ lo, int nq)
{
    for (int i = blockIdx.x * blockDim.x + threadIdx.x; i < nq;
         i += gridDim.x * blockDim.x) {
        float4 v = ((const float4*)src)[i];
        ushort4 h, l;
        split_one(v.x, h.x, l.x);
        split_one(v.y, h.y, l.y);
        split_one(v.z, h.z, l.z);
        split_one(v.w, h.w, l.w);
        ((ushort4*)hi)[i] = h;
        ((ushort4*)lo)[i] = l;
    }
}

// Build padded B for GEMM1: rows 0..1535 = W_qkv, 1536..1543 = W_a, rest 0.
__global__ __launch_bounds__(256) void wcat_split_kernel(
    const float* __restrict__ Wqkv, const float* __restrict__ Wa,
    unsigned short* __restrict__ hi, unsigned short* __restrict__ lo)
{
    int q = blockIdx.x * 256 + threadIdx.x;   // quad index; grid covers exactly
    int row = q >> 8;                         // 256 quads per 1024-col row
    int cq = q & 255;
    float4 v = make_float4(0.f, 0.f, 0.f, 0.f);
    if (row < QKV_N)           v = ((const float4*)(Wqkv + (size_t)row * DIMSZ))[cq];
    else if (row < QKV_N + NH) v = ((const float4*)(Wa + (size_t)(row - QKV_N) * DIMSZ))[cq];
    ushort4 h, l;
    split_one(v.x, h.x, l.x);
    split_one(v.y, h.y, l.y);
    split_one(v.z, h.z, l.z);
    split_one(v.w, h.w, l.w);
    ((ushort4*)hi)[q] = h;
    ((ushort4*)lo)[q] = l;
}

// ---------------------------------------------------------------------------
// Split-bf16 MFMA GEMM: C(MxN) = (Ah+Al)(MxK) * (Wh+Wl)(NxK)^T, dropping lo*lo.
// 128x128 tile, BK=32, 4 waves (2x2), per-wave 64x64 = 4x4 fragments of 16x16.
// LDS is fragment-ordered, lane-linear: subtile fi at fi*1024B, lane l's 16B at
// +l*16 -> exactly global_load_lds's wave-uniform-base + lane*size semantics.
// MODE 0: plain store to out0 (stride DIMSZ). MODE 1: qkv/abuf seam at col 1536.
template<int MODE>
__global__ __launch_bounds__(256) void mfma_gemm_kernel(
    const unsigned short* __restrict__ Ah, const unsigned short* __restrict__ Al,
    const unsigned short* __restrict__ Wh, const unsigned short* __restrict__ Wl,
    float* __restrict__ out0, float* __restrict__ out1, int K)
{
    __shared__ __align__(16) unsigned short Ahs[4096], Als[4096], Bhs[4096], Bls[4096];
    const int tid = threadIdx.x;
    const int lane = tid & 63;
    const int wid = tid >> 6;
    const int wr = wid >> 1, wc = wid & 1;
    const int row0 = blockIdx.y * 128;
    const int col0 = blockIdx.x * 128;
    const int m = lane & 15;        // row within 16-row subtile
    const int kh = lane >> 4;       // which 8-wide k slice of BK=32

    f32x4 acc[4][4] = {};

    for (int k0 = 0; k0 < K; k0 += 32) {
        // stage via async DMA: wave w, pass p covers subtile fi = p*4+w of all
        // four matrices. Per-lane global addr carries the fragment permutation.
        #pragma unroll
        for (int p = 0; p < 2; ++p) {
            int fi = p * 4 + wid;
            size_t ga = (size_t)(row0 + fi * 16 + m) * K + (k0 + kh * 8);
            size_t gb = (size_t)(col0 + fi * 16 + m) * K + (k0 + kh * 8);
            gload16(&Ah[ga], &Ahs[fi * 512]);
            gload16(&Al[ga], &Als[fi * 512]);
            gload16(&Wh[gb], &Bhs[fi * 512]);
            gload16(&Wl[gb], &Bls[fi * 512]);
        }
        __syncthreads();   // compiler drains vmcnt before s_barrier

        bfx8 ah[4], al[4], bh[4], bl[4];
        #pragma unroll
        for (int i = 0; i < 4; ++i) {
            ah[i] = *(const bfx8*)&Ahs[(wr * 4 + i) * 512 + lane * 8];
            al[i] = *(const bfx8*)&Als[(wr * 4 + i) * 512 + lane * 8];
            bh[i] = *(const bfx8*)&Bhs[(wc * 4 + i) * 512 + lane * 8];
            bl[i] = *(const bfx8*)&Bls[(wc * 4 + i) * 512 + lane * 8];
        }
        #pragma unroll
        for (int mi = 0; mi < 4; ++mi)
            #pragma unroll
            for (int ni = 0; ni < 4; ++ni) {
                acc[mi][ni] = __builtin_amdgcn_mfma_f32_16x16x32_bf16(ah[mi], bh[ni], acc[mi][ni], 0, 0, 0);
                acc[mi][ni] = __builtin_amdgcn_mfma_f32_16x16x32_bf16(ah[mi], bl[ni], acc[mi][ni], 0, 0, 0);
                acc[mi][ni] = __builtin_amdgcn_mfma_f32_16x16x32_bf16(al[mi], bh[ni], acc[mi][ni], 0, 0, 0);
            }
        __syncthreads();
    }

    // C/D layout (m89-verified): col = lane&15, row = (lane>>4)*4 + reg
    #pragma unroll
    for (int mi = 0; mi < 4; ++mi)
        #pragma unroll
        for (int ni = 0; ni < 4; ++ni) {
            int crow = row0 + wr * 64 + mi * 16 + (lane >> 4) * 4;
            int ccol = col0 + wc * 64 + ni * 16 + (lane & 15);
            if (MODE == 0) {
                #pragma unroll
                for (int r = 0; r < 4; ++r)
                    out0[(size_t)(crow + r) * DIMSZ + ccol] = acc[mi][ni][r];
            } else {
                if (ccol < QKV_N) {
                    #pragma unroll
                    for (int r = 0; r < 4; ++r)
                        out0[(size_t)(crow + r) * QKV_N + ccol] = acc[mi][ni][r];
                } else if (ccol < QKV_N + NH) {
                    #pragma unroll
                    for (int r = 0; r < 4; ++r)
                        out1[(size_t)(crow + r) * NH + (ccol - QKV_N)] = acc[mi][ni][r];
                }
            }
        }
}

// ---------------------------------------------------------------------------
// Prep: in-place l2norm of q,k head-chunks, silu on v, decay from a.
__global__ __launch_bounds__(64) void prep_kernel(
    float* __restrict__ qkv, float* __restrict__ abuf,
    const float* __restrict__ A_log, const float* __restrict__ dt_bias)
{
    const int row = blockIdx.x;
    const int lane = threadIdx.x;
    float* base = qkv + (size_t)row * QKV_N;

    #pragma unroll
    for (int c = 0; c < 16; ++c) {
        float x = base[c * 64 + lane];
        float s = x * x;
        #pragma unroll
        for (int m = 1; m < 64; m <<= 1) s += __shfl_xor(s, m);
        float inv = 1.0f / sqrtf(s + EPS_F);
        base[c * 64 + lane] = x * inv;
    }
    #pragma unroll
    for (int c = 0; c < 8; ++c) {
        float xv = base[1024 + c * 64 + lane];
        float sg = 1.0f / (1.0f + expf(-xv));
        base[1024 + c * 64 + lane] = xv * sg;
    }
    if (lane < NH) {
        float a = abuf[(size_t)row * NH + lane] + dt_bias[lane];
        float sp = fmaxf(a, 0.0f) + log1pf(expf(-fabsf(a)));
        float d = expf(-expf(A_log[lane]) * sp);
        abuf[(size_t)row * NH + lane] = d;
    }
}

// ---------------------------------------------------------------------------
// Scan: one wave per (b,h,d); lane n owns S[n,d].
// Explicit 8-step double-buffered register prefetch: the compiler refused to
// pipeline (prev round: VGPR_Count=12, ~1208 cy/step = raw memory latency on
// the critical path). Named groups + full unroll = compile-time indices (rule
// #20), loads for group g+1 stay in vmcnt flight under group g's compute.
// OOB prefetch of the final group reads workspace garbage that is never used.
__global__ __launch_bounds__(64) void scan_kernel(
    const float* __restrict__ qkv, const float* __restrict__ dbuf,
    float* __restrict__ outs)
{
    const int bi = blockIdx.x;
    const int d = bi & 63;
    const int h = (bi >> 6) & 7;
    const int b = bi >> 9;
    const int lane = threadIdx.x;

    const size_t qstride = (size_t)B_DIM * QKV_N;    // 6144 floats per t
    const size_t dstride = (size_t)B_DIM * NH;       // 32
    const size_t ostride = (size_t)B_DIM * VAL_DIM;  // 2048
    const size_t qbase = (size_t)b * QKV_N + h * 64 + lane;
    const size_t kbase = qbase + KEY_DIM;
    const size_t vbase = (size_t)b * QKV_N + 1024 + h * 64 + d;
    const size_t dbase = (size_t)b * NH + h;
    size_t obase = (size_t)b * VAL_DIM + h * 64 + d;

    float ka[8], qa[8], va[8], da[8];
    float kb[8], qb[8], vb[8], db[8];
    float S = 0.0f;

#define LOADG(K_, Q_, V_, D_, T0)                                    \
    _Pragma("unroll")                                                \
    for (int j = 0; j < 8; ++j) {                                    \
        size_t t_ = (size_t)(T0) + j;                                \
        K_[j] = qkv[t_ * qstride + kbase];                           \
        Q_[j] = qkv[t_ * qstride + qbase];                           \
        V_[j] = qkv[t_ * qstride + vbase];                           \
        D_[j] = dbuf[t_ * dstride + dbase];                          \
    }

#define COMPG(K_, Q_, V_, D_)                                        \
    _Pragma("unroll")                                                \
    for (int j = 0; j < 8; ++j) {                                    \
        float u = fmaf(D_[j], S, K_[j] * V_[j]);                     \
        float e = __expf(2.0f * u);                                  \
        float r = __builtin_amdgcn_rcpf(e + 1.0f);                   \
        S = fmaf(-2.0f, r, 1.0f);                                    \
        float p = Q_[j] * S;                                         \
        _Pragma("unroll")                                            \
        for (int mm = 1; mm < 64; mm <<= 1) p += __shfl_xor(p, mm);  \
        if (lane == 0) outs[obase] = p;                              \
        obase += ostride;                                            \
    }

    LOADG(ka, qa, va, da, 0)
    for (int g = 0; g < T_DIM / 8; g += 2) {
        LOADG(kb, qb, vb, db, (g + 1) * 8)   // prefetch next group
        COMPG(ka, qa, va, da)                // compute current under the loads
        LOADG(ka, qa, va, da, (g + 2) * 8)   // last iter: harmless OOB into ws
        COMPG(kb, qb, vb, db)
    }
#undef LOADG
#undef COMPG
}

// ---------------------------------------------------------------------------
extern "C" void kernel_launch(void* const* d_in, const int* in_sizes, int n_in,
                              void* d_out, int out_size, void* d_ws, size_t ws_size,
                              hipStream_t stream) {
    const float* x       = (const float*)d_in[0];
    const float* Wqkv    = (const float*)d_in[1];
    const float* Wa      = (const float*)d_in[2];
    const float* A_log   = (const float*)d_in[3];
    const float* dt_bias = (const float*)d_in[4];
    const float* Wout    = (const float*)d_in[5];
    float* out = (float*)d_out;

    char* w = (char*)d_ws;
    float* qkv  = (float*)w;                             // 8192*1536*4 = 50,331,648
    float* abuf = (float*)(w + 50331648);                // 8192*8*4    = 262,144
    float* outs = (float*)(w + 50593792);                // 8192*512*4  = 16,777,216
    unsigned short* xh = (unsigned short*)(w + 67371008);   // 16,777,216
    unsigned short* xl = (unsigned short*)(w + 84148224);   // 16,777,216
    unsigned short* wh = (unsigned short*)(w + 100925440);  // 1664*1024*2 = 3,407,872
    unsigned short* wl = (unsigned short*)(w + 104333312);  // 3,407,872  (end ~102.8 MiB)
    // xh/xl region reused after gemm1 (stream-ordered):
    unsigned short* oh    = (unsigned short*)(w + 67371008); // 8,388,608
    unsigned short* ol    = (unsigned short*)(w + 75759616); // 8,388,608
    unsigned short* wouth = (unsigned short*)(w + 84148224); // 1,048,576
    unsigned short* woutl = (unsigned short*)(w + 85196800); // 1,048,576

    // hi/lo splits of x and [Wqkv;Wa;pad]
    split4_kernel<<<2048, 256, 0, stream>>>(x, xh, xl, ROWS * DIMSZ / 4);
    wcat_split_kernel<<<N1_PAD, 256, 0, stream>>>(Wqkv, Wa, wh, wl);
    // GEMM1: [8192 x 1024] * [1664 x 1024]^T -> qkv + abuf
    mfma_gemm_kernel<1><<<dim3(N1_PAD / 128, ROWS / 128), 256, 0, stream>>>(
        xh, xl, wh, wl, qkv, abuf, DIMSZ);
    prep_kernel<<<ROWS, 64, 0, stream>>>(qkv, abuf, A_log, dt_bias);
    scan_kernel<<<B_DIM * NH * 64, 64, 0, stream>>>(qkv, abuf, outs);
    // splits for GEMM2 (reuse x-split region)
    split4_kernel<<<1024, 256, 0, stream>>>(outs, oh, ol, ROWS * VAL_DIM / 4);
    split4_kernel<<<512, 256, 0, stream>>>(Wout, wouth, woutl, DIMSZ * VAL_DIM / 4);
    // GEMM2: [8192 x 512] * [1024 x 512]^T -> out
    mfma_gemm_kernel<0><<<dim3(DIMSZ / 128, ROWS / 128), 256, 0, stream>>>(
        oh, ol, wouth, woutl, out, nullptr, VAL_DIM);
}

// Round 7
// 831.311 us; speedup vs baseline: 1.5747x; 1.1140x over previous
//
#include <hip/hip_runtime.h>
#include <math.h>

// E88 FLA Hybrid: split-bf16 MFMA qkv GEMM -> prep (packs scan layout) ->
// tanh scan (XCD-swizzled, L1/L2-local) -> split-bf16 MFMA out GEMM
// T=2048 B=4 DIM=1024 H=8 NS=64 HV=64 KEY_DIM=512 VAL_DIM=512

#define T_DIM 2048
#define B_DIM 4
#define DIMSZ 1024
#define NH 8
#define KEY_DIM 512
#define VAL_DIM 512
#define ROWS (T_DIM * B_DIM)   // 8192
#define QKV_N 1536
#define N1_PAD 1664            // 13 * 128 (qkv 1536 + a 8 + zero pad)
#define EPS_F 1e-6f

typedef __attribute__((ext_vector_type(8))) short bfx8;   // 8 bf16 in 4 VGPRs
typedef __attribute__((ext_vector_type(4))) float f32x4;  // MFMA accumulator

// ---------------------------------------------------------------------------
// async global->LDS, 16B per lane; LDS dest = wave-uniform base + lane*16
__device__ __forceinline__ void gload16(const void* g, void* l) {
    __builtin_amdgcn_global_load_lds(
        (const __attribute__((address_space(1))) void*)g,
        (__attribute__((address_space(3))) void*)l, 16, 0, 0);
}

// RNE f32 -> bf16 (bit pattern) + the rounded-back float
__device__ __forceinline__ unsigned short bf16_rne(float x, float& back) {
    unsigned int u = __float_as_uint(x);
    unsigned int r = u + 0x7FFFu + ((u >> 16) & 1u);
    unsigned short h = (unsigned short)(r >> 16);
    back = __uint_as_float((unsigned int)h << 16);
    return h;
}

__device__ __forceinline__ void split_one(float x, unsigned short& h, unsigned short& l) {
    float hf;
    h = bf16_rne(x, hf);
    float rem = x - hf;
    float lf;
    l = bf16_rne(rem, lf);
}

// ---------------------------------------------------------------------------
// Generic f32 -> (hi,lo) bf16 split, float4-vectorized, grid-stride.
__global__ __launch_bounds__(256) void split4_kernel(
    const float* __restrict__ src, unsigned short* __restrict__ hi,
    unsigned short* __restrict__ lo, int nq)
{
    for (int i = blockIdx.x * blockDim.x + threadIdx.x; i < nq;
         i += gridDim.x * blockDim.x) {
        float4 v = ((const float4*)src)[i];
        ushort4 h, l;
        split_one(v.x, h.x, l.x);
        split_one(v.y, h.y, l.y);
        split_one(v.z, h.z, l.z);
        split_one(v.w, h.w, l.w);
        ((ushort4*)hi)[i] = h;
        ((ushort4*)lo)[i] = l;
    }
}

// Build padded B for GEMM1: rows 0..1535 = W_qkv, 1536..1543 = W_a, rest 0.
__global__ __launch_bounds__(256) void wcat_split_kernel(
    const float* __restrict__ Wqkv, const float* __restrict__ Wa,
    unsigned short* __restrict__ hi, unsigned short* __restrict__ lo)
{
    int q = blockIdx.x * 256 + threadIdx.x;   // quad index; grid covers exactly
    int row = q >> 8;                         // 256 quads per 1024-col row
    int cq = q & 255;
    float4 v = make_float4(0.f, 0.f, 0.f, 0.f);
    if (row < QKV_N)           v = ((const float4*)(Wqkv + (size_t)row * DIMSZ))[cq];
    else if (row < QKV_N + NH) v = ((const float4*)(Wa + (size_t)(row - QKV_N) * DIMSZ))[cq];
    ushort4 h, l;
    split_one(v.x, h.x, l.x);
    split_one(v.y, h.y, l.y);
    split_one(v.z, h.z, l.z);
    split_one(v.w, h.w, l.w);
    ((ushort4*)hi)[q] = h;
    ((ushort4*)lo)[q] = l;
}

// ---------------------------------------------------------------------------
// Split-bf16 MFMA GEMM: C(MxN) = (Ah+Al)(MxK) * (Wh+Wl)(NxK)^T, dropping lo*lo.
// 128x128 tile, BK=32, 4 waves (2x2), per-wave 64x64 = 4x4 fragments of 16x16.
// LDS is fragment-ordered, lane-linear -> global_load_lds dwordx4 staging.
// MODE 0: plain store to out0 (stride DIMSZ). MODE 1: qkv/abuf seam at col 1536.
template<int MODE>
__global__ __launch_bounds__(256) void mfma_gemm_kernel(
    const unsigned short* __restrict__ Ah, const unsigned short* __restrict__ Al,
    const unsigned short* __restrict__ Wh, const unsigned short* __restrict__ Wl,
    float* __restrict__ out0, float* __restrict__ out1, int K)
{
    __shared__ __align__(16) unsigned short Ahs[4096], Als[4096], Bhs[4096], Bls[4096];
    const int tid = threadIdx.x;
    const int lane = tid & 63;
    const int wid = tid >> 6;
    const int wr = wid >> 1, wc = wid & 1;
    const int row0 = blockIdx.y * 128;
    const int col0 = blockIdx.x * 128;
    const int m = lane & 15;        // row within 16-row subtile
    const int kh = lane >> 4;       // which 8-wide k slice of BK=32

    f32x4 acc[4][4] = {};

    for (int k0 = 0; k0 < K; k0 += 32) {
        #pragma unroll
        for (int p = 0; p < 2; ++p) {
            int fi = p * 4 + wid;
            size_t ga = (size_t)(row0 + fi * 16 + m) * K + (k0 + kh * 8);
            size_t gb = (size_t)(col0 + fi * 16 + m) * K + (k0 + kh * 8);
            gload16(&Ah[ga], &Ahs[fi * 512]);
            gload16(&Al[ga], &Als[fi * 512]);
            gload16(&Wh[gb], &Bhs[fi * 512]);
            gload16(&Wl[gb], &Bls[fi * 512]);
        }
        __syncthreads();

        bfx8 ah[4], al[4], bh[4], bl[4];
        #pragma unroll
        for (int i = 0; i < 4; ++i) {
            ah[i] = *(const bfx8*)&Ahs[(wr * 4 + i) * 512 + lane * 8];
            al[i] = *(const bfx8*)&Als[(wr * 4 + i) * 512 + lane * 8];
            bh[i] = *(const bfx8*)&Bhs[(wc * 4 + i) * 512 + lane * 8];
            bl[i] = *(const bfx8*)&Bls[(wc * 4 + i) * 512 + lane * 8];
        }
        #pragma unroll
        for (int mi = 0; mi < 4; ++mi)
            #pragma unroll
            for (int ni = 0; ni < 4; ++ni) {
                acc[mi][ni] = __builtin_amdgcn_mfma_f32_16x16x32_bf16(ah[mi], bh[ni], acc[mi][ni], 0, 0, 0);
                acc[mi][ni] = __builtin_amdgcn_mfma_f32_16x16x32_bf16(ah[mi], bl[ni], acc[mi][ni], 0, 0, 0);
                acc[mi][ni] = __builtin_amdgcn_mfma_f32_16x16x32_bf16(al[mi], bh[ni], acc[mi][ni], 0, 0, 0);
            }
        __syncthreads();
    }

    // C/D layout (m89-verified): col = lane&15, row = (lane>>4)*4 + reg
    #pragma unroll
    for (int mi = 0; mi < 4; ++mi)
        #pragma unroll
        for (int ni = 0; ni < 4; ++ni) {
            int crow = row0 + wr * 64 + mi * 16 + (lane >> 4) * 4;
            int ccol = col0 + wc * 64 + ni * 16 + (lane & 15);
            if (MODE == 0) {
                #pragma unroll
                for (int r = 0; r < 4; ++r)
                    out0[(size_t)(crow + r) * DIMSZ + ccol] = acc[mi][ni][r];
            } else {
                if (ccol < QKV_N) {
                    #pragma unroll
                    for (int r = 0; r < 4; ++r)
                        out0[(size_t)(crow + r) * QKV_N + ccol] = acc[mi][ni][r];
                } else if (ccol < QKV_N + NH) {
                    #pragma unroll
                    for (int r = 0; r < 4; ++r)
                        out1[(size_t)(crow + r) * NH + (ccol - QKV_N)] = acc[mi][ni][r];
                }
            }
        }
}

// ---------------------------------------------------------------------------
// Prep: reads raw qkv row (t,b), l2norms q/k, silus v, computes decay, and
// REPACKS the row in place to scan layout: head h at h*192 = {k[64],q[64],v[64]}.
// Lane-private mod-64 columns: every read and write of lane l is at offset
// == l (mod 64), so the in-place permutation has no cross-lane hazard.
__global__ __launch_bounds__(64) void prep_kernel(
    float* __restrict__ qkv, float* __restrict__ abuf,
    const float* __restrict__ A_log, const float* __restrict__ dt_bias)
{
    const int row = blockIdx.x;       // t*B + b
    const int lane = threadIdx.x;
    float* base = qkv + (size_t)row * QKV_N;

    float xq[8], xk[8], xv[8];
    #pragma unroll
    for (int hh = 0; hh < 8; ++hh) {
        xq[hh] = base[hh * 64 + lane];
        xk[hh] = base[512 + hh * 64 + lane];
        xv[hh] = base[1024 + hh * 64 + lane];
    }
    #pragma unroll
    for (int hh = 0; hh < 8; ++hh) {
        float sq = xq[hh] * xq[hh];
        float sk = xk[hh] * xk[hh];
        #pragma unroll
        for (int m = 1; m < 64; m <<= 1) {
            sq += __shfl_xor(sq, m);
            sk += __shfl_xor(sk, m);
        }
        xq[hh] *= 1.0f / sqrtf(sq + EPS_F);
        xk[hh] *= 1.0f / sqrtf(sk + EPS_F);
        float sg = 1.0f / (1.0f + expf(-xv[hh]));
        xv[hh] *= sg;
    }
    if (lane < NH) {
        float a = abuf[(size_t)row * NH + lane] + dt_bias[lane];
        float sp = fmaxf(a, 0.0f) + log1pf(expf(-fabsf(a)));
        float dcy = expf(-expf(A_log[lane]) * sp);
        abuf[(size_t)row * NH + lane] = dcy;
    }
    #pragma unroll
    for (int hh = 0; hh < 8; ++hh) {
        base[hh * 192 + lane]       = xk[hh];
        base[hh * 192 + 64 + lane]  = xq[hh];
        base[hh * 192 + 128 + lane] = xv[hh];
    }
}

// ---------------------------------------------------------------------------
// Scan: 512 blocks x 4 waves; block = (b,h,dq), wave = d = dq*4+wid; lane = n.
// XCD swizzle: xcd = (b*8+h)&7 so all waves of one (b,h) panel share one XCD's
// L2 (k/q/v lines fetched from HBM once -> L2/L1 hits for the rest).
// Explicit 8-step double-buffered register prefetch as before.
__global__ __launch_bounds__(256) void scan_kernel(
    const float* __restrict__ sbuf, const float* __restrict__ dbuf,
    float* __restrict__ outs)
{
    const int bid = blockIdx.x;
    const int xcd = bid & 7;
    const int rr = bid >> 3;
    const int gi = rr >> 4;
    const int dq = rr & 15;
    const int g = (gi << 3) | xcd;
    const int b = g >> 3;
    const int h = g & 7;
    const int wid = threadIdx.x >> 6;
    const int lane = threadIdx.x & 63;
    const int d = dq * 4 + wid;

    const size_t rstride = (size_t)B_DIM * QKV_N;    // 6144 floats per t
    const size_t base0 = (size_t)b * QKV_N + h * 192;
    const size_t dstride = (size_t)B_DIM * NH;       // 32
    const size_t dbase = (size_t)b * NH + h;
    const size_t ostride = (size_t)B_DIM * VAL_DIM;  // 2048
    size_t obase = (size_t)b * VAL_DIM + h * 64 + d;

    float ka[8], qa[8], va[8], da[8];
    float kb[8], qb[8], vb[8], db[8];
    float S = 0.0f;

#define LOADG(K_, Q_, V_, D_, T0)                                    \
    {                                                                \
        int t0_ = (T0);                                              \
        if (t0_ > T_DIM - 8) t0_ = T_DIM - 8;                        \
        _Pragma("unroll")                                            \
        for (int j = 0; j < 8; ++j) {                                \
            size_t bb = (size_t)(t0_ + j) * rstride + base0;         \
            K_[j] = sbuf[bb + lane];                                 \
            Q_[j] = sbuf[bb + 64 + lane];                            \
            V_[j] = sbuf[bb + 128 + d];                              \
            D_[j] = dbuf[(size_t)(t0_ + j) * dstride + dbase];       \
        }                                                            \
    }

#define COMPG(K_, Q_, V_, D_)                                        \
    _Pragma("unroll")                                                \
    for (int j = 0; j < 8; ++j) {                                    \
        float u = fmaf(D_[j], S, K_[j] * V_[j]);                     \
        float e = __expf(2.0f * u);                                  \
        float r = __builtin_amdgcn_rcpf(e + 1.0f);                   \
        S = fmaf(-2.0f, r, 1.0f);                                    \
        float p = Q_[j] * S;                                         \
        _Pragma("unroll")                                            \
        for (int mm = 1; mm < 64; mm <<= 1) p += __shfl_xor(p, mm);  \
        if (lane == 0) outs[obase] = p;                              \
        obase += ostride;                                            \
    }

    LOADG(ka, qa, va, da, 0)
    for (int gg = 0; gg < T_DIM / 8; gg += 2) {
        LOADG(kb, qb, vb, db, (gg + 1) * 8)   // prefetch next group
        COMPG(ka, qa, va, da)                 // compute current under the loads
        LOADG(ka, qa, va, da, (gg + 2) * 8)   // final iter clamps to last group
        COMPG(kb, qb, vb, db)
    }
#undef LOADG
#undef COMPG
}

// ---------------------------------------------------------------------------
extern "C" void kernel_launch(void* const* d_in, const int* in_sizes, int n_in,
                              void* d_out, int out_size, void* d_ws, size_t ws_size,
                              hipStream_t stream) {
    const float* x       = (const float*)d_in[0];
    const float* Wqkv    = (const float*)d_in[1];
    const float* Wa      = (const float*)d_in[2];
    const float* A_log   = (const float*)d_in[3];
    const float* dt_bias = (const float*)d_in[4];
    const float* Wout    = (const float*)d_in[5];
    float* out = (float*)d_out;

    char* w = (char*)d_ws;
    float* qkv  = (float*)w;                             // 8192*1536*4 = 50,331,648
    float* abuf = (float*)(w + 50331648);                // 8192*8*4    = 262,144
    float* outs = (float*)(w + 50593792);                // 8192*512*4  = 16,777,216
    unsigned short* xh = (unsigned short*)(w + 67371008);   // 16,777,216
    unsigned short* xl = (unsigned short*)(w + 84148224);   // 16,777,216
    unsigned short* wh = (unsigned short*)(w + 100925440);  // 1664*1024*2 = 3,407,872
    unsigned short* wl = (unsigned short*)(w + 104333312);  // 3,407,872  (end ~102.8 MiB)
    // xh/xl region reused after gemm1 (stream-ordered):
    unsigned short* oh    = (unsigned short*)(w + 67371008); // 8,388,608
    unsigned short* ol    = (unsigned short*)(w + 75759616); // 8,388,608
    unsigned short* wouth = (unsigned short*)(w + 84148224); // 1,048,576
    unsigned short* woutl = (unsigned short*)(w + 85196800); // 1,048,576

    // hi/lo splits of x and [Wqkv;Wa;pad]
    split4_kernel<<<2048, 256, 0, stream>>>(x, xh, xl, ROWS * DIMSZ / 4);
    wcat_split_kernel<<<N1_PAD, 256, 0, stream>>>(Wqkv, Wa, wh, wl);
    // GEMM1: [8192 x 1024] * [1664 x 1024]^T -> qkv + abuf
    mfma_gemm_kernel<1><<<dim3(N1_PAD / 128, ROWS / 128), 256, 0, stream>>>(
        xh, xl, wh, wl, qkv, abuf, DIMSZ);
    // prep: l2norm/silu/decay + in-place repack to scan layout
    prep_kernel<<<ROWS, 64, 0, stream>>>(qkv, abuf, A_log, dt_bias);
    // scan: 512 blocks (b,h,dq) x 4 waves
    scan_kernel<<<512, 256, 0, stream>>>(qkv, abuf, outs);
    // splits for GEMM2 (reuse x-split region)
    split4_kernel<<<1024, 256, 0, stream>>>(outs, oh, ol, ROWS * VAL_DIM / 4);
    split4_kernel<<<512, 256, 0, stream>>>(Wout, wouth, woutl, DIMSZ * VAL_DIM / 4);
    // GEMM2: [8192 x 512] * [1024 x 512]^T -> out
    mfma_gemm_kernel<0><<<dim3(DIMSZ / 128, ROWS / 128), 256, 0, stream>>>(
        oh, ol, wouth, woutl, out, nullptr, VAL_DIM);
}

// Round 8
// 609.864 us; speedup vs baseline: 2.1465x; 1.3631x over previous
//
#include <hip/hip_runtime.h>
#include <math.h>

// E88 FLA Hybrid: split-bf16 MFMA qkv GEMM -> prep (packs scan layout) ->
// tanh scan (XCD-swizzled, batched select-tree reduce) -> split-bf16 MFMA out GEMM
// T=2048 B=4 DIM=1024 H=8 NS=64 HV=64 KEY_DIM=512 VAL_DIM=512

#define T_DIM 2048
#define B_DIM 4
#define DIMSZ 1024
#define NH 8
#define KEY_DIM 512
#define VAL_DIM 512
#define ROWS (T_DIM * B_DIM)   // 8192
#define QKV_N 1536
#define N1_PAD 1664            // 13 * 128 (qkv 1536 + a 8 + zero pad)
#define EPS_F 1e-6f

typedef __attribute__((ext_vector_type(8))) short bfx8;   // 8 bf16 in 4 VGPRs
typedef __attribute__((ext_vector_type(4))) float f32x4;  // MFMA accumulator

// ---------------------------------------------------------------------------
// async global->LDS, 16B per lane; LDS dest = wave-uniform base + lane*16
__device__ __forceinline__ void gload16(const void* g, void* l) {
    __builtin_amdgcn_global_load_lds(
        (const __attribute__((address_space(1))) void*)g,
        (__attribute__((address_space(3))) void*)l, 16, 0, 0);
}

// RNE f32 -> bf16 (bit pattern) + the rounded-back float
__device__ __forceinline__ unsigned short bf16_rne(float x, float& back) {
    unsigned int u = __float_as_uint(x);
    unsigned int r = u + 0x7FFFu + ((u >> 16) & 1u);
    unsigned short h = (unsigned short)(r >> 16);
    back = __uint_as_float((unsigned int)h << 16);
    return h;
}

__device__ __forceinline__ void split_one(float x, unsigned short& h, unsigned short& l) {
    float hf;
    h = bf16_rne(x, hf);
    float rem = x - hf;
    float lf;
    l = bf16_rne(rem, lf);
}

// ---------------------------------------------------------------------------
// Generic f32 -> (hi,lo) bf16 split, float4-vectorized, grid-stride.
__global__ __launch_bounds__(256) void split4_kernel(
    const float* __restrict__ src, unsigned short* __restrict__ hi,
    unsigned short* __restrict__ lo, int nq)
{
    for (int i = blockIdx.x * blockDim.x + threadIdx.x; i < nq;
         i += gridDim.x * blockDim.x) {
        float4 v = ((const float4*)src)[i];
        ushort4 h, l;
        split_one(v.x, h.x, l.x);
        split_one(v.y, h.y, l.y);
        split_one(v.z, h.z, l.z);
        split_one(v.w, h.w, l.w);
        ((ushort4*)hi)[i] = h;
        ((ushort4*)lo)[i] = l;
    }
}

// Build padded B for GEMM1: rows 0..1535 = W_qkv, 1536..1543 = W_a, rest 0.
__global__ __launch_bounds__(256) void wcat_split_kernel(
    const float* __restrict__ Wqkv, const float* __restrict__ Wa,
    unsigned short* __restrict__ hi, unsigned short* __restrict__ lo)
{
    int q = blockIdx.x * 256 + threadIdx.x;   // quad index; grid covers exactly
    int row = q >> 8;                         // 256 quads per 1024-col row
    int cq = q & 255;
    float4 v = make_float4(0.f, 0.f, 0.f, 0.f);
    if (row < QKV_N)           v = ((const float4*)(Wqkv + (size_t)row * DIMSZ))[cq];
    else if (row < QKV_N + NH) v = ((const float4*)(Wa + (size_t)(row - QKV_N) * DIMSZ))[cq];
    ushort4 h, l;
    split_one(v.x, h.x, l.x);
    split_one(v.y, h.y, l.y);
    split_one(v.z, h.z, l.z);
    split_one(v.w, h.w, l.w);
    ((ushort4*)hi)[q] = h;
    ((ushort4*)lo)[q] = l;
}

// ---------------------------------------------------------------------------
// Split-bf16 MFMA GEMM: C(MxN) = (Ah+Al)(MxK) * (Wh+Wl)(NxK)^T, dropping lo*lo.
// 128x128 tile, BK=32, 4 waves (2x2), per-wave 64x64 = 4x4 fragments of 16x16.
// LDS is fragment-ordered, lane-linear -> global_load_lds dwordx4 staging.
// MODE 0: plain store to out0 (stride DIMSZ). MODE 1: qkv/abuf seam at col 1536.
template<int MODE>
__global__ __launch_bounds__(256) void mfma_gemm_kernel(
    const unsigned short* __restrict__ Ah, const unsigned short* __restrict__ Al,
    const unsigned short* __restrict__ Wh, const unsigned short* __restrict__ Wl,
    float* __restrict__ out0, float* __restrict__ out1, int K)
{
    __shared__ __align__(16) unsigned short Ahs[4096], Als[4096], Bhs[4096], Bls[4096];
    const int tid = threadIdx.x;
    const int lane = tid & 63;
    const int wid = tid >> 6;
    const int wr = wid >> 1, wc = wid & 1;
    const int row0 = blockIdx.y * 128;
    const int col0 = blockIdx.x * 128;
    const int m = lane & 15;        // row within 16-row subtile
    const int kh = lane >> 4;       // which 8-wide k slice of BK=32

    f32x4 acc[4][4] = {};

    for (int k0 = 0; k0 < K; k0 += 32) {
        #pragma unroll
        for (int p = 0; p < 2; ++p) {
            int fi = p * 4 + wid;
            size_t ga = (size_t)(row0 + fi * 16 + m) * K + (k0 + kh * 8);
            size_t gb = (size_t)(col0 + fi * 16 + m) * K + (k0 + kh * 8);
            gload16(&Ah[ga], &Ahs[fi * 512]);
            gload16(&Al[ga], &Als[fi * 512]);
            gload16(&Wh[gb], &Bhs[fi * 512]);
            gload16(&Wl[gb], &Bls[fi * 512]);
        }
        __syncthreads();

        bfx8 ah[4], al[4], bh[4], bl[4];
        #pragma unroll
        for (int i = 0; i < 4; ++i) {
            ah[i] = *(const bfx8*)&Ahs[(wr * 4 + i) * 512 + lane * 8];
            al[i] = *(const bfx8*)&Als[(wr * 4 + i) * 512 + lane * 8];
            bh[i] = *(const bfx8*)&Bhs[(wc * 4 + i) * 512 + lane * 8];
            bl[i] = *(const bfx8*)&Bls[(wc * 4 + i) * 512 + lane * 8];
        }
        #pragma unroll
        for (int mi = 0; mi < 4; ++mi)
            #pragma unroll
            for (int ni = 0; ni < 4; ++ni) {
                acc[mi][ni] = __builtin_amdgcn_mfma_f32_16x16x32_bf16(ah[mi], bh[ni], acc[mi][ni], 0, 0, 0);
                acc[mi][ni] = __builtin_amdgcn_mfma_f32_16x16x32_bf16(ah[mi], bl[ni], acc[mi][ni], 0, 0, 0);
                acc[mi][ni] = __builtin_amdgcn_mfma_f32_16x16x32_bf16(al[mi], bh[ni], acc[mi][ni], 0, 0, 0);
            }
        __syncthreads();
    }

    // C/D layout (m89-verified): col = lane&15, row = (lane>>4)*4 + reg
    #pragma unroll
    for (int mi = 0; mi < 4; ++mi)
        #pragma unroll
        for (int ni = 0; ni < 4; ++ni) {
            int crow = row0 + wr * 64 + mi * 16 + (lane >> 4) * 4;
            int ccol = col0 + wc * 64 + ni * 16 + (lane & 15);
            if (MODE == 0) {
                #pragma unroll
                for (int r = 0; r < 4; ++r)
                    out0[(size_t)(crow + r) * DIMSZ + ccol] = acc[mi][ni][r];
            } else {
                if (ccol < QKV_N) {
                    #pragma unroll
                    for (int r = 0; r < 4; ++r)
                        out0[(size_t)(crow + r) * QKV_N + ccol] = acc[mi][ni][r];
                } else if (ccol < QKV_N + NH) {
                    #pragma unroll
                    for (int r = 0; r < 4; ++r)
                        out1[(size_t)(crow + r) * NH + (ccol - QKV_N)] = acc[mi][ni][r];
                }
            }
        }
}

// ---------------------------------------------------------------------------
// Prep: reads raw qkv row (t,b), l2norms q/k, silus v, computes decay, and
// REPACKS the row in place to scan layout: head h at h*192 = {k[64],q[64],v[64]}.
// Lane-private mod-64 columns -> no cross-lane hazard in-place.
__global__ __launch_bounds__(64) void prep_kernel(
    float* __restrict__ qkv, float* __restrict__ abuf,
    const float* __restrict__ A_log, const float* __restrict__ dt_bias)
{
    const int row = blockIdx.x;       // t*B + b
    const int lane = threadIdx.x;
    float* base = qkv + (size_t)row * QKV_N;

    float xq[8], xk[8], xv[8];
    #pragma unroll
    for (int hh = 0; hh < 8; ++hh) {
        xq[hh] = base[hh * 64 + lane];
        xk[hh] = base[512 + hh * 64 + lane];
        xv[hh] = base[1024 + hh * 64 + lane];
    }
    #pragma unroll
    for (int hh = 0; hh < 8; ++hh) {
        float sq = xq[hh] * xq[hh];
        float sk = xk[hh] * xk[hh];
        #pragma unroll
        for (int m = 1; m < 64; m <<= 1) {
            sq += __shfl_xor(sq, m);
            sk += __shfl_xor(sk, m);
        }
        xq[hh] *= 1.0f / sqrtf(sq + EPS_F);
        xk[hh] *= 1.0f / sqrtf(sk + EPS_F);
        float sg = 1.0f / (1.0f + expf(-xv[hh]));
        xv[hh] *= sg;
    }
    if (lane < NH) {
        float a = abuf[(size_t)row * NH + lane] + dt_bias[lane];
        float sp = fmaxf(a, 0.0f) + log1pf(expf(-fabsf(a)));
        float dcy = expf(-expf(A_log[lane]) * sp);
        abuf[(size_t)row * NH + lane] = dcy;
    }
    #pragma unroll
    for (int hh = 0; hh < 8; ++hh) {
        base[hh * 192 + lane]       = xk[hh];
        base[hh * 192 + 64 + lane]  = xq[hh];
        base[hh * 192 + 128 + lane] = xv[hh];
    }
}

// ---------------------------------------------------------------------------
// Scan: 512 blocks x 4 waves; block=(b,h,dq), wave d=dq*4+wid, lane=n.
// XCD swizzle keeps each (b,h) panel on one XCD's L2 (FETCH 265->27MB r7).
// Per 8-step batch: S-chain + per-lane partials p[0..7] (pure VALU), then a
// select-tree multi-reduce: xor(1,2,4) per value -> 7 cndmask select of
// t[lane&7] -> xor(8,16,32) once -> lane j<8 holds the total for step t0+j.
// 30 shfl per 8 outputs (vs 48) and all chains independent/batched.
__global__ __launch_bounds__(256) void scan_kernel(
    const float* __restrict__ sbuf, const float* __restrict__ dbuf,
    float* __restrict__ outs)
{
    const int bid = blockIdx.x;
    const int xcd = bid & 7;
    const int rr = bid >> 3;
    const int gi = rr >> 4;
    const int dq = rr & 15;
    const int g = (gi << 3) | xcd;
    const int b = g >> 3;
    const int h = g & 7;
    const int wid = threadIdx.x >> 6;
    const int lane = threadIdx.x & 63;
    const int d = dq * 4 + wid;

    const size_t rstride = (size_t)B_DIM * QKV_N;    // 6144 floats per t
    const size_t base0 = (size_t)b * QKV_N + h * 192;
    const size_t dstride = (size_t)B_DIM * NH;       // 32
    const size_t dbase = (size_t)b * NH + h;
    const size_t ostride = (size_t)B_DIM * VAL_DIM;  // 2048
    const size_t obase = (size_t)b * VAL_DIM + h * 64 + d;

    float ka[8], qa[8], va[8], da[8];
    float kb[8], qb[8], vb[8], db[8];
    float S = 0.0f;

#define LOADG(K_, Q_, V_, D_, T0)                                    \
    {                                                                \
        int t0_ = (T0);                                              \
        if (t0_ > T_DIM - 8) t0_ = T_DIM - 8;                        \
        _Pragma("unroll")                                            \
        for (int j = 0; j < 8; ++j) {                                \
            size_t bb = (size_t)(t0_ + j) * rstride + base0;         \
            K_[j] = sbuf[bb + lane];                                 \
            Q_[j] = sbuf[bb + 64 + lane];                            \
            V_[j] = sbuf[bb + 128 + d];                              \
            D_[j] = dbuf[(size_t)(t0_ + j) * dstride + dbase];       \
        }                                                            \
    }

#define COMPB(K_, Q_, V_, D_, T0)                                    \
    {                                                                \
        float p[8];                                                  \
        _Pragma("unroll")                                            \
        for (int j = 0; j < 8; ++j) {                                \
            float u = fmaf(D_[j], S, K_[j] * V_[j]);                 \
            float e = __expf(2.0f * u);                              \
            float r = __builtin_amdgcn_rcpf(e + 1.0f);               \
            S = fmaf(-2.0f, r, 1.0f);                                \
            p[j] = Q_[j] * S;                                        \
        }                                                            \
        _Pragma("unroll")                                            \
        for (int j = 0; j < 8; ++j) {                                \
            float x = p[j];                                          \
            x += __shfl_xor(x, 1);                                   \
            x += __shfl_xor(x, 2);                                   \
            x += __shfl_xor(x, 4);                                   \
            p[j] = x;   /* chunk (lane>>3) partial, replicated */    \
        }                                                            \
        float m0 = (lane & 1) ? p[1] : p[0];                         \
        float m1 = (lane & 1) ? p[3] : p[2];                         \
        float m2 = (lane & 1) ? p[5] : p[4];                         \
        float m3 = (lane & 1) ? p[7] : p[6];                         \
        float n0 = (lane & 2) ? m1 : m0;                             \
        float n1 = (lane & 2) ? m3 : m2;                             \
        float sel = (lane & 4) ? n1 : n0;  /* t[lane&7] */           \
        sel += __shfl_xor(sel, 8);                                   \
        sel += __shfl_xor(sel, 16);                                  \
        sel += __shfl_xor(sel, 32);        /* total[lane&7] */       \
        if (lane < 8)                                                \
            outs[(size_t)((T0) + lane) * ostride + obase] = sel;     \
    }

    LOADG(ka, qa, va, da, 0)
    for (int gg = 0; gg < T_DIM / 8; gg += 2) {
        LOADG(kb, qb, vb, db, (gg + 1) * 8)   // prefetch next batch
        COMPB(ka, qa, va, da, gg * 8)         // compute current under the loads
        LOADG(ka, qa, va, da, (gg + 2) * 8)   // final iter clamps (dummy)
        COMPB(kb, qb, vb, db, (gg + 1) * 8)
    }
#undef LOADG
#undef COMPB
}

// ---------------------------------------------------------------------------
extern "C" void kernel_launch(void* const* d_in, const int* in_sizes, int n_in,
                              void* d_out, int out_size, void* d_ws, size_t ws_size,
                              hipStream_t stream) {
    const float* x       = (const float*)d_in[0];
    const float* Wqkv    = (const float*)d_in[1];
    const float* Wa      = (const float*)d_in[2];
    const float* A_log   = (const float*)d_in[3];
    const float* dt_bias = (const float*)d_in[4];
    const float* Wout    = (const float*)d_in[5];
    float* out = (float*)d_out;

    char* w = (char*)d_ws;
    float* qkv  = (float*)w;                             // 8192*1536*4 = 50,331,648
    float* abuf = (float*)(w + 50331648);                // 8192*8*4    = 262,144
    float* outs = (float*)(w + 50593792);                // 8192*512*4  = 16,777,216
    unsigned short* xh = (unsigned short*)(w + 67371008);   // 16,777,216
    unsigned short* xl = (unsigned short*)(w + 84148224);   // 16,777,216
    unsigned short* wh = (unsigned short*)(w + 100925440);  // 1664*1024*2 = 3,407,872
    unsigned short* wl = (unsigned short*)(w + 104333312);  // 3,407,872  (end ~102.8 MiB)
    // xh/xl region reused after gemm1 (stream-ordered):
    unsigned short* oh    = (unsigned short*)(w + 67371008); // 8,388,608
    unsigned short* ol    = (unsigned short*)(w + 75759616); // 8,388,608
    unsigned short* wouth = (unsigned short*)(w + 84148224); // 1,048,576
    unsigned short* woutl = (unsigned short*)(w + 85196800); // 1,048,576

    // hi/lo splits of x and [Wqkv;Wa;pad]
    split4_kernel<<<2048, 256, 0, stream>>>(x, xh, xl, ROWS * DIMSZ / 4);
    wcat_split_kernel<<<N1_PAD, 256, 0, stream>>>(Wqkv, Wa, wh, wl);
    // GEMM1: [8192 x 1024] * [1664 x 1024]^T -> qkv + abuf
    mfma_gemm_kernel<1><<<dim3(N1_PAD / 128, ROWS / 128), 256, 0, stream>>>(
        xh, xl, wh, wl, qkv, abuf, DIMSZ);
    // prep: l2norm/silu/decay + in-place repack to scan layout
    prep_kernel<<<ROWS, 64, 0, stream>>>(qkv, abuf, A_log, dt_bias);
    // scan: 512 blocks (b,h,dq) x 4 waves
    scan_kernel<<<512, 256, 0, stream>>>(qkv, abuf, outs);
    // splits for GEMM2 (reuse x-split region)
    split4_kernel<<<1024, 256, 0, stream>>>(outs, oh, ol, ROWS * VAL_DIM / 4);
    split4_kernel<<<512, 256, 0, stream>>>(Wout, wouth, woutl, DIMSZ * VAL_DIM / 4);
    // GEMM2: [8192 x 512] * [1024 x 512]^T -> out
    mfma_gemm_kernel<0><<<dim3(DIMSZ / 128, ROWS / 128), 256, 0, stream>>>(
        oh, ol, wouth, woutl, out, nullptr, VAL_DIM);
}